// Round 4
// baseline (457.380 us; speedup 1.0000x reference)
//
#include <hip/hip_runtime.h>
#include <math.h>

#define EPSF 1e-12f

// N=64, C=512, P=1600, K=64
// R7: fused pipeline, occupancy-fixed.
//   k0 : Wb[k][c] = bf16(W); zeros asum.
//   kf : FUSED GEMM1+softmax+GEMM2. Grid (5 p-chunks of 320, 64 n), 512 thr.
//        R7: subtile 32 p (10 per chunk), LDS 71 KB -> 2 blocks/CU resident
//        (R6 was 99.8 KB -> 1/CU -> all-idle latency collapse: occ 15.8%,
//        HBM 8.5%, Mfma 2.3%). Waves = pt(2) x ch(4): each phase-1 wave does
//        128 c (kc=4), accb combine has 3 writer quarters.
//        Phases per subtile: [stage+GEMM1] bar [combine+softmax+a' on waves 0-1]
//        bar [GEMM2 K=32 all waves] bar.  Softmax/a'/frag/store code verbatim.
//   k4 : merged epilogue per n (R6-verified, unchanged).
// ws: part @0 (41,943,040) | Wb @41,943,040 (65,536) | asum @42,008,576

typedef short bf16x8 __attribute__((ext_vector_type(8)));
typedef float f32x4  __attribute__((ext_vector_type(4)));

__device__ __forceinline__ ushort f2b(float x) {
    unsigned u = __float_as_uint(x);
    return (ushort)((u + 0x7fffu + ((u >> 16) & 1u)) >> 16);
}

// ------------------------------------------------- K0: Wb[k][c] = bf16(W), asum=0
__global__ __launch_bounds__(256) void k0_wb(const float* __restrict__ W,
                                             ushort* __restrict__ Wb,
                                             float* __restrict__ asum) {
    int i = blockIdx.x * 256 + threadIdx.x;
    if (i < 64 * 512) Wb[i] = f2b(W[i]);
    if (i < 64 * 64) asum[i] = 0.f;
}

// ------------------------------------------------- KF: fused GEMM1+softmax+GEMM2
// LDS: xs[512 c][40 p] bf16 (32-p subtile, pad 40) = 40960 B; abuf[64 k][40] =
// 5120 B; accb[2 pt][3][4 nt][64][4] f32 = 24576 B; ssb[4 ch][2 pt][16] = 512 B.
// Total 71168 B -> 2 blocks/CU (all 320 blocks co-resident).
__global__ __launch_bounds__(512, 4) void kf(const float* __restrict__ x,
                                             const ushort* __restrict__ Wb,
                                             float* __restrict__ part,
                                             float* __restrict__ asum) {
    const int cb = blockIdx.x;           // p-chunk 0..4 (320 p each)
    const int n  = blockIdx.y;
    const int wv = threadIdx.x >> 6, lane = threadIdx.x & 63;
    const int q = lane >> 4, l15 = lane & 15;
    const int pt = wv & 1, ch = wv >> 1; // p-tile 0..1 (16 p), c-quarter 0..3 (128 c)
    const int cw = wv * 64;              // GEMM2 c-range per wave

    __shared__ ushort xs[512 * 40];
    __shared__ ushort abuf[64 * 40];
    __shared__ float  accb[2 * 3 * 4 * 64 * 4];  // [pt][ch-1][nt][lane][4]
    __shared__ float  ssb[4 * 2 * 16];           // [ch][pt][l15]

    f32x4 acc2[4][4] = {};               // GEMM2 acc: [k-mt][c-nt], lives all subtiles

    const ushort* wrow = Wb + l15 * 512 + ch * 128 + q * 8;

    for (int s = 0; s < 10; s++) {
        // ---------- phase 1: stage + GEMM1 partial (all waves), c-quarter = ch
        const float* xq = x + (size_t)n * 819200 + (size_t)(ch * 128 + q * 8) * 1600
                            + (size_t)cb * 320 + s * 32 + pt * 16 + l15;
        f32x4 acc1[4] = {};
        float ssp = 0.f;
        float fv[2][8];
        #pragma unroll
        for (int j = 0; j < 8; j++) fv[0][j] = xq[(size_t)j * 1600];
        #pragma unroll
        for (int kc = 0; kc < 4; kc++) {
            const int cur = kc & 1, nxt = cur ^ 1;
            if (kc < 3) {
                #pragma unroll
                for (int j = 0; j < 8; j++)
                    fv[nxt][j] = xq[(size_t)((kc + 1) * 32 + j) * 1600];
            }
            bf16x8 af;
            #pragma unroll
            for (int j = 0; j < 8; j++) {
                float f = fv[cur][j];
                ssp = fmaf(f, f, ssp);          // fp32-accurate sum of squares
                ushort b = f2b(f);
                af[j] = (short)b;
                xs[(ch * 128 + kc * 32 + q * 8 + j) * 40 + pt * 16 + l15] = b;
            }
            #pragma unroll
            for (int nt = 0; nt < 4; nt++) {
                bf16x8 bw = *(const bf16x8*)(wrow + nt * 16 * 512 + kc * 32);
                acc1[nt] = __builtin_amdgcn_mfma_f32_16x16x32_bf16(af, bw, acc1[nt], 0, 0, 0);
            }
        }
        // ss over this wave's q-groups (covers its 128-c quarter)
        ssp += __shfl_xor(ssp, 16, 64);
        ssp += __shfl_xor(ssp, 32, 64);
        if (lane < 16) ssb[ch * 32 + pt * 16 + lane] = ssp;
        if (ch != 0) {
            #pragma unroll
            for (int nt = 0; nt < 4; nt++)
                *(f32x4*)&accb[(((pt * 3 + (ch - 1)) * 4 + nt) * 64 + lane) * 4] = acc1[nt];
        }
        __syncthreads();  // accb/ssb/xs(s) visible

        // ---------- phase 2: combine quarters + softmax + a' (waves 0-1)
        if (ch == 0) {
            #pragma unroll
            for (int e = 0; e < 3; e++)
                #pragma unroll
                for (int nt = 0; nt < 4; nt++)
                    acc1[nt] += *(const f32x4*)&accb[(((pt * 3 + e) * 4 + nt) * 64 + lane) * 4];
            float sst = ssb[pt * 16 + l15] + ssb[32 + pt * 16 + l15]
                      + ssb[64 + pt * 16 + l15] + ssb[96 + pt * 16 + l15];
            float rn_l = 1.f / fmaxf(sqrtf(sst), EPSF);
            float rnv[4];
            #pragma unroll
            for (int r = 0; r < 4; r++) rnv[r] = __shfl(rn_l, q * 4 + r, 64);

            // softmax over k (4 nt in-lane x 16 l15 cross-lane)  [R1/R3-verified]
            float v[4][4];
            float mx[4] = {-3.4e38f, -3.4e38f, -3.4e38f, -3.4e38f};
            #pragma unroll
            for (int nt = 0; nt < 4; nt++)
                #pragma unroll
                for (int r = 0; r < 4; r++) {
                    v[nt][r] = acc1[nt][r] * rnv[r];
                    mx[r] = fmaxf(mx[r], v[nt][r]);
                }
            #pragma unroll
            for (int sh = 1; sh <= 8; sh <<= 1)
                #pragma unroll
                for (int r = 0; r < 4; r++) mx[r] = fmaxf(mx[r], __shfl_xor(mx[r], sh, 64));
            float sm[4] = {0.f, 0.f, 0.f, 0.f};
            #pragma unroll
            for (int nt = 0; nt < 4; nt++)
                #pragma unroll
                for (int r = 0; r < 4; r++) { v[nt][r] = __expf(v[nt][r] - mx[r]); sm[r] += v[nt][r]; }
            #pragma unroll
            for (int sh = 1; sh <= 8; sh <<= 1)
                #pragma unroll
                for (int r = 0; r < 4; r++) sm[r] += __shfl_xor(sm[r], sh, 64);
            float inv[4];
            #pragma unroll
            for (int r = 0; r < 4; r++) inv[r] = 1.f / sm[r];
            #pragma unroll
            for (int nt = 0; nt < 4; nt++)
                #pragma unroll
                for (int r = 0; r < 4; r++) v[nt][r] *= inv[r];

            // asum partials (sum of a over this wave's 16 p)
            #pragma unroll
            for (int nt = 0; nt < 4; nt++) {
                float t = v[nt][0] + v[nt][1] + v[nt][2] + v[nt][3];
                t += __shfl_xor(t, 16, 64);
                t += __shfl_xor(t, 32, 64);
                if (lane < 16) atomicAdd(&asum[n * 64 + nt * 16 + lane], t);
            }

            // a' = a*rn -> bf16 into abuf[k][40] (4 consecutive p packed)
            #pragma unroll
            for (int nt = 0; nt < 4; nt++) {
                ushort4 pk;
                pk.x = f2b(v[nt][0] * rnv[0]);
                pk.y = f2b(v[nt][1] * rnv[1]);
                pk.z = f2b(v[nt][2] * rnv[2]);
                pk.w = f2b(v[nt][3] * rnv[3]);
                *(ushort4*)&abuf[(nt * 16 + l15) * 40 + pt * 16 + q * 4] = pk;
            }
        }
        __syncthreads();  // abuf visible

        // ---------- phase 3: GEMM2 K=32 from LDS (all waves)  [R6-verified mapping]
        {
            bf16x8 av[4];
            #pragma unroll
            for (int mt = 0; mt < 4; mt++)
                av[mt] = *(const bf16x8*)&abuf[(mt * 16 + l15) * 40 + q * 8];
            bf16x8 bv[4];
            #pragma unroll
            for (int nt = 0; nt < 4; nt++)
                bv[nt] = *(const bf16x8*)&xs[(cw + nt * 16 + l15) * 40 + q * 8];
            #pragma unroll
            for (int mt = 0; mt < 4; mt++)
                #pragma unroll
                for (int nt = 0; nt < 4; nt++)
                    acc2[mt][nt] = __builtin_amdgcn_mfma_f32_16x16x32_bf16(av[mt], bv[nt], acc2[mt][nt], 0, 0, 0);
        }
        __syncthreads();  // xs/abuf/accb free for next subtile
    }

    // partial slab store: part[cb][n][k][c], sole owner -> plain stores
    float* ob = part + ((size_t)cb * 64 + n) * 32768 + cw + l15;
    #pragma unroll
    for (int mt = 0; mt < 4; mt++)
        #pragma unroll
        for (int nt = 0; nt < 4; nt++)
            #pragma unroll
            for (int r = 0; r < 4; r++)
                ob[(mt * 16 + q * 4 + r) * 512 + nt * 16] = acc2[mt][nt][r];
}

// ------------------------------------------------- K4: merged epilogue per n
// sum 5 partials -> vlad rows in LDS -> rownorm2 -> gn -> normalize -> out.
__global__ __launch_bounds__(512) void k4(const float* __restrict__ part,
                                          const float* __restrict__ asum,
                                          const float* __restrict__ cent,
                                          float* __restrict__ out) {
    const int n = blockIdx.x;
    const int wv = threadIdx.x >> 6, lane = threadIdx.x & 63;
    __shared__ float stash[64 * 512];
    __shared__ float rs[64];
    __shared__ float gsh;

    #pragma unroll
    for (int i = 0; i < 8; i++) {
        const int k = wv * 8 + i;
        const size_t ro = (size_t)n * 32768 + (size_t)k * 512 + lane * 8;
        const float as = asum[n * 64 + k];
        f32x4 a0 = {}, a1 = {};
        #pragma unroll
        for (int cbk = 0; cbk < 5; cbk++) {
            const f32x4* pp = (const f32x4*)(part + (size_t)cbk * 2097152 + ro);
            a0 += pp[0];
            a1 += pp[1];
        }
        const f32x4* cp = (const f32x4*)(cent + k * 512 + lane * 8);
        f32x4 v0 = a0 - cp[0] * as;
        f32x4 v1 = a1 - cp[1] * as;
        float s = 0.f;
        #pragma unroll
        for (int e = 0; e < 4; e++) { s = fmaf(v0[e], v0[e], s); s = fmaf(v1[e], v1[e], s); }
        *(f32x4*)&stash[k * 512 + lane * 8] = v0;
        *(f32x4*)&stash[k * 512 + lane * 8 + 4] = v1;
        #pragma unroll
        for (int off = 32; off > 0; off >>= 1) s += __shfl_down(s, off, 64);
        if (lane == 0) rs[k] = s;
    }
    __syncthreads();
    if (wv == 0) {
        float t = rs[lane];
        float d = fmaxf(sqrtf(t), EPSF);
        float r = t / (d * d);
        #pragma unroll
        for (int off = 32; off > 0; off >>= 1) r += __shfl_down(r, off, 64);
        if (lane == 0) gsh = fmaxf(sqrtf(r), EPSF);
    }
    __syncthreads();
    const float g = gsh;
    #pragma unroll
    for (int i = 0; i < 8; i++) {
        const int k = wv * 8 + i;
        const float inv = 1.f / (fmaxf(sqrtf(rs[k]), EPSF) * g);
        f32x4 v0 = *(const f32x4*)&stash[k * 512 + lane * 8];
        f32x4 v1 = *(const f32x4*)&stash[k * 512 + lane * 8 + 4];
        v0 *= inv;
        v1 *= inv;
        float* op = out + (size_t)n * 32768 + (size_t)k * 512 + lane * 8;
        *(f32x4*)op = v0;
        *(f32x4*)(op + 4) = v1;
    }
}

// -------------------------------------------------
extern "C" void kernel_launch(void* const* d_in, const int* in_sizes, int n_in,
                              void* d_out, int out_size, void* d_ws, size_t ws_size,
                              hipStream_t stream) {
    const float* x    = (const float*)d_in[0];
    const float* W    = (const float*)d_in[1];
    const float* cent = (const float*)d_in[2];
    float* out = (float*)d_out;
    char* ws = (char*)d_ws;

    float*  part = (float*)(ws + 0);            // 5 * 64 * 32768 * 4 = 41,943,040
    ushort* Wb   = (ushort*)(ws + 41943040);    // 65,536
    float*  asum = (float*)(ws + 42008576);     // 16,384

    hipLaunchKernelGGL(k0_wb, dim3(128),   dim3(256), 0, stream, W, Wb, asum);
    hipLaunchKernelGGL(kf,    dim3(5, 64), dim3(512), 0, stream, x, Wb, part, asum);
    hipLaunchKernelGGL(k4,    dim3(64),    dim3(512), 0, stream, part, asum, cent, out);
}

// Round 5
// 397.615 us; speedup vs baseline: 1.1503x; 1.1503x over previous
//
#include <hip/hip_runtime.h>
#include <math.h>

#define EPSF 1e-12f

// N=64, C=512, P=1600, K=64
// R8: revert to R5 split (fusion refuted by R6/R7 counters: barrier-drained,
// grid-starved, 0.5-1.7 TB/s effective). Split + two R6/R7-derived wins:
//   k0 : Wb[k][c] = bf16(W); zeros asum.
//   k2g: GEMM1 + softmax + a_t  (R5-verified, 25 waves/CU, unchanged).
//   k3g: GEMM2, full-K direct store (R4-verified) + R8 XCD-grouping swizzle:
//        the 4 c-tile blocks of each n land on ONE XCD (xcd = n&7) so x[n]
//        (3.3 MB) + a_t[n] (0.2 MB) stream through that XCD's 4 MB L2 once.
//   k4 : merged one-pass epilogue (R6-verified structure, reads raw slab
//        directly): sum->sub->rownorm2->gn->normalize, vlad stashed in LDS.
// ws: a_t bf16 @0 (13,107,200) | Wb @13,107,200 | asum @13,172,736

typedef short bf16x8 __attribute__((ext_vector_type(8)));
typedef float f32x4  __attribute__((ext_vector_type(4)));

__device__ __forceinline__ ushort f2b(float x) {
    unsigned u = __float_as_uint(x);
    return (ushort)((u + 0x7fffu + ((u >> 16) & 1u)) >> 16);
}

// ------------------------------------------------- K0: Wb[k][c] = bf16(W), asum=0
__global__ __launch_bounds__(256) void k0_wb(const float* __restrict__ W,
                                             ushort* __restrict__ Wb,
                                             float* __restrict__ asum) {
    int i = blockIdx.x * 256 + threadIdx.x;
    if (i < 64 * 512) Wb[i] = f2b(W[i]);
    if (i < 64 * 64) asum[i] = 0.f;
}

// ------------------------------------------------- K2g: GEMM1 + softmax + a_t
// grid (25 ptiles of 64, 64 n), 256 thr. Wave: D[16p][64k], K=512 c.  [R5-verified]
__global__ __launch_bounds__(256) void k2g_gemm1(const float* __restrict__ x,
                                                 const ushort* __restrict__ Wb,
                                                 ushort* __restrict__ a_t,
                                                 float* __restrict__ asum) {
    const int n = blockIdx.y;
    const int p0 = blockIdx.x * 64;
    const int wv = threadIdx.x >> 6, lane = threadIdx.x & 63;
    const int q = lane >> 4, l15 = lane & 15;
    const int pw = p0 + wv * 16;

    // A-frag source: x[n][c = kc*32 + q*8 + j][pw + l15]  (lanes coalesced in p)
    const float* xq = x + (size_t)n * 512 * 1600 + (size_t)q * 8 * 1600 + pw + l15;
    const ushort* brow = Wb + l15 * 512 + q * 8;

    f32x4 acc[4] = {};
    float ssp = 0.f;

    // 2-deep software pipeline (statically indexed via full unroll).
    float fv[2][8];
    bf16x8 bwv[2][4];
    #pragma unroll
    for (int j = 0; j < 8; j++) fv[0][j] = xq[(size_t)j * 1600];
    #pragma unroll
    for (int nt = 0; nt < 4; nt++) bwv[0][nt] = *(const bf16x8*)(brow + nt * 16 * 512);

    #pragma unroll
    for (int kc = 0; kc < 16; kc++) {
        const int cur = kc & 1, nxt = cur ^ 1;
        if (kc < 15) {
            #pragma unroll
            for (int j = 0; j < 8; j++)
                fv[nxt][j] = xq[(size_t)((kc + 1) * 32 + j) * 1600];
            #pragma unroll
            for (int nt = 0; nt < 4; nt++)
                bwv[nxt][nt] = *(const bf16x8*)(brow + nt * 16 * 512 + (kc + 1) * 32);
        }
        bf16x8 af;
        #pragma unroll
        for (int j = 0; j < 8; j++) {
            float f = fv[cur][j];
            ssp = fmaf(f, f, ssp);             // fp32-accurate sum of squares
            af[j] = (short)f2b(f);
        }
        #pragma unroll
        for (int nt = 0; nt < 4; nt++)
            acc[nt] = __builtin_amdgcn_mfma_f32_16x16x32_bf16(af, bwv[cur][nt], acc[nt], 0, 0, 0);
    }

    // complete ss across the 4 q-lanes sharing p-row l15
    ssp += __shfl_xor(ssp, 16, 64);
    ssp += __shfl_xor(ssp, 32, 64);
    float rn_l = 1.f / fmaxf(sqrtf(ssp), EPSF);
    float rnv[4];
    #pragma unroll
    for (int r = 0; r < 4; r++) rnv[r] = __shfl(rn_l, q * 4 + r, 64);  // rn for D-row q*4+r

    // softmax over k (4 nt in-lane x 16 l15 cross-lane)  [R1/R3-verified]
    float v[4][4];
    float mx[4] = {-3.4e38f, -3.4e38f, -3.4e38f, -3.4e38f};
    #pragma unroll
    for (int nt = 0; nt < 4; nt++)
        #pragma unroll
        for (int r = 0; r < 4; r++) {
            v[nt][r] = acc[nt][r] * rnv[r];
            mx[r] = fmaxf(mx[r], v[nt][r]);
        }
    #pragma unroll
    for (int s = 1; s <= 8; s <<= 1)
        #pragma unroll
        for (int r = 0; r < 4; r++) mx[r] = fmaxf(mx[r], __shfl_xor(mx[r], s, 64));
    float sm[4] = {0.f, 0.f, 0.f, 0.f};
    #pragma unroll
    for (int nt = 0; nt < 4; nt++)
        #pragma unroll
        for (int r = 0; r < 4; r++) { v[nt][r] = __expf(v[nt][r] - mx[r]); sm[r] += v[nt][r]; }
    #pragma unroll
    for (int s = 1; s <= 8; s <<= 1)
        #pragma unroll
        for (int r = 0; r < 4; r++) sm[r] += __shfl_xor(sm[r], s, 64);
    float inv[4];
    #pragma unroll
    for (int r = 0; r < 4; r++) inv[r] = 1.f / sm[r];
    #pragma unroll
    for (int nt = 0; nt < 4; nt++)
        #pragma unroll
        for (int r = 0; r < 4; r++) v[nt][r] *= inv[r];

    // asum partials: column k = nt*16 + l15, sum over this wave's 16 p-rows
    #pragma unroll
    for (int nt = 0; nt < 4; nt++) {
        float t = v[nt][0] + v[nt][1] + v[nt][2] + v[nt][3];
        t += __shfl_xor(t, 16, 64);
        t += __shfl_xor(t, 32, 64);
        if (lane < 16) atomicAdd(&asum[n * 64 + nt * 16 + lane], t);
    }

    // a' = a*rn -> bf16, LDS bounce [k][p_local], then b128 global write  [R2-verified]
    __shared__ ushort abuf[4][64 * 24];
    #pragma unroll
    for (int nt = 0; nt < 4; nt++)
        #pragma unroll
        for (int r = 0; r < 4; r++)
            abuf[wv][(nt * 16 + l15) * 24 + q * 4 + r] = f2b(v[nt][r] * rnv[r]);
    __syncthreads();
    ushort* dst = a_t + ((size_t)n * 64 + lane) * 1600 + pw;
    const ushort* srcl = &abuf[wv][lane * 24];
    *(uint4*)(dst)     = *(const uint4*)(srcl);
    *(uint4*)(dst + 8) = *(const uint4*)(srcl + 8);
}

// ------------------------------------------------- K3g: GEMM2  [R4-verified + R8 swizzle]
// D[k][c]: block 64k x 128c, full K=1600 p. grid 256 linear, 512 thr = 8 waves.
// R8: decode so the 4 c-tiles of each n share one XCD (believed id%8 round-robin;
// if the mapping differs this is perf-neutral, never incorrect):
//   id = (n&7) + 8*(ct + 4*(n>>3))  ->  xcd = id&7 = n&7 for all 4 ct.
__global__ __launch_bounds__(512) void k3_gemm2(const ushort* __restrict__ a_t,
                                                const float* __restrict__ x,
                                                float* __restrict__ out) {
    const int id = blockIdx.x;
    const int xcd = id & 7, slot = id >> 3;
    const int ct = slot & 3, ng = slot >> 2;
    const int n = ng * 8 + xcd;
    const int c0 = ct * 128;
    const int wv = threadIdx.x >> 6, lane = threadIdx.x & 63;
    const int q = lane >> 4, l15 = lane & 15;
    const int cw = c0 + wv * 16;

    const ushort* abase = a_t + ((size_t)n * 64 + l15) * 1600 + q * 8;
    const float*  xbase = x + ((size_t)n * 512 + cw + l15) * 1600 + q * 8;

    f32x4 acc[4] = {};
    #pragma unroll 2
    for (int pc = 0; pc < 1600; pc += 32) {
        bf16x8 af[4];
        #pragma unroll
        for (int mt = 0; mt < 4; mt++)
            af[mt] = *(const bf16x8*)(abase + (size_t)mt * 16 * 1600 + pc);
        const float* xr = xbase + pc;
        float4 f0 = *(const float4*)(xr);
        float4 f1 = *(const float4*)(xr + 4);
        bf16x8 b;
        b[0] = (short)f2b(f0.x); b[1] = (short)f2b(f0.y);
        b[2] = (short)f2b(f0.z); b[3] = (short)f2b(f0.w);
        b[4] = (short)f2b(f1.x); b[5] = (short)f2b(f1.y);
        b[6] = (short)f2b(f1.z); b[7] = (short)f2b(f1.w);
        #pragma unroll
        for (int mt = 0; mt < 4; mt++)
            acc[mt] = __builtin_amdgcn_mfma_f32_16x16x32_bf16(af[mt], b, acc[mt], 0, 0, 0);
    }
    // D row = k = mt*16 + q*4 + r, col = c = cw + l15. Sole owner -> plain store.
    float* ob = out + (size_t)n * 32768 + cw + l15;
    #pragma unroll
    for (int mt = 0; mt < 4; mt++)
        #pragma unroll
        for (int r = 0; r < 4; r++)
            ob[(mt * 16 + q * 4 + r) * 512] = acc[mt][r];
}

// ------------------------------------------------- K4: merged one-pass epilogue
// per-n block: read raw slab, subtract asum*cent, rownorm2, gn, normalize, write.
// Structure R6-verified (part-sum removed). vraw aliases out (read-before-write
// within the block's own n-slab, separated by barriers).
__global__ __launch_bounds__(512) void k4(const float* __restrict__ vraw,
                                          const float* __restrict__ asum,
                                          const float* __restrict__ cent,
                                          float* __restrict__ out) {
    const int n = blockIdx.x;
    const int wv = threadIdx.x >> 6, lane = threadIdx.x & 63;
    __shared__ float stash[64 * 512];
    __shared__ float rs[64];
    __shared__ float gsh;

    #pragma unroll
    for (int i = 0; i < 8; i++) {
        const int k = wv * 8 + i;
        const size_t ro = (size_t)n * 32768 + (size_t)k * 512 + lane * 8;
        const float as = asum[n * 64 + k];
        const f32x4* pp = (const f32x4*)(vraw + ro);
        f32x4 a0 = pp[0], a1 = pp[1];
        const f32x4* cp = (const f32x4*)(cent + k * 512 + lane * 8);
        f32x4 v0 = a0 - cp[0] * as;
        f32x4 v1 = a1 - cp[1] * as;
        float s = 0.f;
        #pragma unroll
        for (int e = 0; e < 4; e++) { s = fmaf(v0[e], v0[e], s); s = fmaf(v1[e], v1[e], s); }
        *(f32x4*)&stash[k * 512 + lane * 8] = v0;
        *(f32x4*)&stash[k * 512 + lane * 8 + 4] = v1;
        #pragma unroll
        for (int off = 32; off > 0; off >>= 1) s += __shfl_down(s, off, 64);
        if (lane == 0) rs[k] = s;
    }
    __syncthreads();
    if (wv == 0) {
        float t = rs[lane];
        float d = fmaxf(sqrtf(t), EPSF);
        float r = t / (d * d);
        #pragma unroll
        for (int off = 32; off > 0; off >>= 1) r += __shfl_down(r, off, 64);
        if (lane == 0) gsh = fmaxf(sqrtf(r), EPSF);
    }
    __syncthreads();
    const float g = gsh;
    #pragma unroll
    for (int i = 0; i < 8; i++) {
        const int k = wv * 8 + i;
        const float inv = 1.f / (fmaxf(sqrtf(rs[k]), EPSF) * g);
        f32x4 v0 = *(const f32x4*)&stash[k * 512 + lane * 8];
        f32x4 v1 = *(const f32x4*)&stash[k * 512 + lane * 8 + 4];
        v0 *= inv;
        v1 *= inv;
        float* op = out + (size_t)n * 32768 + (size_t)k * 512 + lane * 8;
        *(f32x4*)op = v0;
        *(f32x4*)(op + 4) = v1;
    }
}

// -------------------------------------------------
extern "C" void kernel_launch(void* const* d_in, const int* in_sizes, int n_in,
                              void* d_out, int out_size, void* d_ws, size_t ws_size,
                              hipStream_t stream) {
    const float* x    = (const float*)d_in[0];
    const float* W    = (const float*)d_in[1];
    const float* cent = (const float*)d_in[2];
    float* out = (float*)d_out;
    char* ws = (char*)d_ws;

    ushort* a_t  = (ushort*)(ws + 0);
    ushort* Wb   = (ushort*)(ws + 13107200);
    float*  asum = (float*)(ws + 13172736);

    hipLaunchKernelGGL(k0_wb,     dim3(128),    dim3(256), 0, stream, W, Wb, asum);
    hipLaunchKernelGGL(k2g_gemm1, dim3(25, 64), dim3(256), 0, stream, x, Wb, a_t, asum);
    hipLaunchKernelGGL(k3_gemm2,  dim3(256),    dim3(512), 0, stream, a_t, x, out);
    hipLaunchKernelGGL(k4,        dim3(64),     dim3(512), 0, stream, out, asum, cent, out);
}

// Round 8
// 383.048 us; speedup vs baseline: 1.1941x; 1.0380x over previous
//
#include <hip/hip_runtime.h>
#include <math.h>

#define EPSF 1e-12f

// N=64, C=512, P=1600, K=64
// R10: R8 split pipeline; k2g rewritten as PAIR-TILE float2 loader.
//   k0 : Wb[k][c] = bf16(W); zeros asum.
//   k2g: GEMM1 + softmax + a_t. R10: each lane loads float2 (two p per lane:
//        even/odd), giving 128-B segments per 16-lane group (was 64-B scalar)
//        and HALF the request count. Two MFMA tiles (even p / odd p) share the
//        same B-frags; per-p arithmetic is bit-identical to R8 (absmax canary).
//        128 thr/block (2 waves of 32 p), grid (25,64) unchanged.
//   k3g: GEMM2 full-K direct store + XCD swizzle (R8-verified, CONTROL).
//   k4 : merged one-pass epilogue (R8-verified).
// NOTE: R9's duplicate-launch diagnostic dropped after 2 infra failures.
// ws: a_t bf16 @0 (13,107,200) | Wb @13,107,200 | asum @13,172,736

typedef short bf16x8 __attribute__((ext_vector_type(8)));
typedef float f32x4  __attribute__((ext_vector_type(4)));

__device__ __forceinline__ ushort f2b(float x) {
    unsigned u = __float_as_uint(x);
    return (ushort)((u + 0x7fffu + ((u >> 16) & 1u)) >> 16);
}

// ------------------------------------------------- K0: Wb[k][c] = bf16(W), asum=0
__global__ __launch_bounds__(256) void k0_wb(const float* __restrict__ W,
                                             ushort* __restrict__ Wb,
                                             float* __restrict__ asum) {
    int i = blockIdx.x * 256 + threadIdx.x;
    if (i < 64 * 512) Wb[i] = f2b(W[i]);
    if (i < 64 * 64) asum[i] = 0.f;
}

// ------------------------------------------------- K2g: GEMM1 + softmax + a_t
// grid (25 ptiles of 64, 64 n), 128 thr = 2 waves x 32 p. Wave: two D[16p][64k]
// tiles (even/odd p interleave), K=512 c.
__global__ __launch_bounds__(128) void k2g_gemm1(const float* __restrict__ x,
                                                 const ushort* __restrict__ Wb,
                                                 ushort* __restrict__ a_t,
                                                 float* __restrict__ asum) {
    const int n = blockIdx.y;
    const int p0 = blockIdx.x * 64;
    const int wv = threadIdx.x >> 6, lane = threadIdx.x & 63;
    const int q = lane >> 4, l15 = lane & 15;
    const int pw = p0 + wv * 32;

    // float2 source: x[n][c = kc*32 + q*8 + j][pw + 2*l15 (+1)]
    // 16 lanes x 8 B = 128-B segment per c-row (full lines, half the requests).
    const float* xq = x + (size_t)n * 819200 + (size_t)q * 8 * 1600 + pw + 2 * l15;
    const ushort* brow = Wb + l15 * 512 + q * 8;

    f32x4 acce[4] = {}, acco[4] = {};
    float sspe = 0.f, sspo = 0.f;

    // 2-deep software pipeline (statically indexed via full unroll).
    float2 fv[2][8];
    bf16x8 bwv[2][4];
    #pragma unroll
    for (int j = 0; j < 8; j++) fv[0][j] = *(const float2*)(xq + (size_t)j * 1600);
    #pragma unroll
    for (int nt = 0; nt < 4; nt++) bwv[0][nt] = *(const bf16x8*)(brow + nt * 16 * 512);

    #pragma unroll
    for (int kc = 0; kc < 16; kc++) {
        const int cur = kc & 1, nxt = cur ^ 1;
        if (kc < 15) {
            #pragma unroll
            for (int j = 0; j < 8; j++)
                fv[nxt][j] = *(const float2*)(xq + (size_t)((kc + 1) * 32 + j) * 1600);
            #pragma unroll
            for (int nt = 0; nt < 4; nt++)
                bwv[nxt][nt] = *(const bf16x8*)(brow + nt * 16 * 512 + (kc + 1) * 32);
        }
        bf16x8 afe, afo;
        #pragma unroll
        for (int j = 0; j < 8; j++) {
            float fe = fv[cur][j].x, fo = fv[cur][j].y;
            sspe = fmaf(fe, fe, sspe);          // fp32-accurate sum of squares
            sspo = fmaf(fo, fo, sspo);
            afe[j] = (short)f2b(fe);
            afo[j] = (short)f2b(fo);
        }
        #pragma unroll
        for (int nt = 0; nt < 4; nt++) {
            acce[nt] = __builtin_amdgcn_mfma_f32_16x16x32_bf16(afe, bwv[cur][nt], acce[nt], 0, 0, 0);
            acco[nt] = __builtin_amdgcn_mfma_f32_16x16x32_bf16(afo, bwv[cur][nt], acco[nt], 0, 0, 0);
        }
    }

    // complete ss across the 4 q-lanes sharing p-row l15 (per tile)
    sspe += __shfl_xor(sspe, 16, 64);
    sspe += __shfl_xor(sspe, 32, 64);
    sspo += __shfl_xor(sspo, 16, 64);
    sspo += __shfl_xor(sspo, 32, 64);
    float rne_l = 1.f / fmaxf(sqrtf(sspe), EPSF);
    float rno_l = 1.f / fmaxf(sqrtf(sspo), EPSF);
    float rnve[4], rnvo[4];
    #pragma unroll
    for (int r = 0; r < 4; r++) {
        rnve[r] = __shfl(rne_l, q * 4 + r, 64);  // rn for D-row q*4+r (even tile)
        rnvo[r] = __shfl(rno_l, q * 4 + r, 64);  // odd tile
    }

    // softmax over k (4 nt in-lane x 16 l15 cross-lane)  [R1/R3-verified, x2 tiles]
    float ve[4][4], vo[4][4];
    float mxe[4] = {-3.4e38f, -3.4e38f, -3.4e38f, -3.4e38f};
    float mxo[4] = {-3.4e38f, -3.4e38f, -3.4e38f, -3.4e38f};
    #pragma unroll
    for (int nt = 0; nt < 4; nt++)
        #pragma unroll
        for (int r = 0; r < 4; r++) {
            ve[nt][r] = acce[nt][r] * rnve[r];
            vo[nt][r] = acco[nt][r] * rnvo[r];
            mxe[r] = fmaxf(mxe[r], ve[nt][r]);
            mxo[r] = fmaxf(mxo[r], vo[nt][r]);
        }
    #pragma unroll
    for (int s = 1; s <= 8; s <<= 1)
        #pragma unroll
        for (int r = 0; r < 4; r++) {
            mxe[r] = fmaxf(mxe[r], __shfl_xor(mxe[r], s, 64));
            mxo[r] = fmaxf(mxo[r], __shfl_xor(mxo[r], s, 64));
        }
    float sme[4] = {0.f, 0.f, 0.f, 0.f}, smo[4] = {0.f, 0.f, 0.f, 0.f};
    #pragma unroll
    for (int nt = 0; nt < 4; nt++)
        #pragma unroll
        for (int r = 0; r < 4; r++) {
            ve[nt][r] = __expf(ve[nt][r] - mxe[r]); sme[r] += ve[nt][r];
            vo[nt][r] = __expf(vo[nt][r] - mxo[r]); smo[r] += vo[nt][r];
        }
    #pragma unroll
    for (int s = 1; s <= 8; s <<= 1)
        #pragma unroll
        for (int r = 0; r < 4; r++) {
            sme[r] += __shfl_xor(sme[r], s, 64);
            smo[r] += __shfl_xor(smo[r], s, 64);
        }
    float inve[4], invo[4];
    #pragma unroll
    for (int r = 0; r < 4; r++) { inve[r] = 1.f / sme[r]; invo[r] = 1.f / smo[r]; }
    #pragma unroll
    for (int nt = 0; nt < 4; nt++)
        #pragma unroll
        for (int r = 0; r < 4; r++) { ve[nt][r] *= inve[r]; vo[nt][r] *= invo[r]; }

    // asum partials: column k = nt*16 + l15, sum over this wave's 32 p-rows
    #pragma unroll
    for (int nt = 0; nt < 4; nt++) {
        float t = ve[nt][0] + ve[nt][1] + ve[nt][2] + ve[nt][3]
                + vo[nt][0] + vo[nt][1] + vo[nt][2] + vo[nt][3];
        t += __shfl_xor(t, 16, 64);
        t += __shfl_xor(t, 32, 64);
        if (lane < 16) atomicAdd(&asum[n * 64 + nt * 16 + lane], t);
    }

    // a' = a*rn -> bf16, LDS bounce [k][p_local 0..31] (pad 36), global b128 write
    __shared__ ushort abuf[2][64 * 36];
    #pragma unroll
    for (int nt = 0; nt < 4; nt++)
        #pragma unroll
        for (int r = 0; r < 4; r++) {
            abuf[wv][(nt * 16 + l15) * 36 + 2 * (q * 4 + r)]     = f2b(ve[nt][r] * rnve[r]);
            abuf[wv][(nt * 16 + l15) * 36 + 2 * (q * 4 + r) + 1] = f2b(vo[nt][r] * rnvo[r]);
        }
    __syncthreads();
    ushort* dst = a_t + ((size_t)n * 64 + lane) * 1600 + pw;
    const ushort* srcl = &abuf[wv][lane * 36];
    *(uint4*)(dst)      = *(const uint4*)(srcl);
    *(uint4*)(dst + 8)  = *(const uint4*)(srcl + 8);
    *(uint4*)(dst + 16) = *(const uint4*)(srcl + 16);
    *(uint4*)(dst + 24) = *(const uint4*)(srcl + 24);
}

// ------------------------------------------------- K3g: GEMM2  [R8-verified, CONTROL]
// D[k][c]: block 64k x 128c, full K=1600 p. grid 256 linear, 512 thr = 8 waves.
__global__ __launch_bounds__(512) void k3_gemm2(const ushort* __restrict__ a_t,
                                                const float* __restrict__ x,
                                                float* __restrict__ out) {
    const int id = blockIdx.x;
    const int xcd = id & 7, slot = id >> 3;
    const int ct = slot & 3, ng = slot >> 2;
    const int n = ng * 8 + xcd;
    const int c0 = ct * 128;
    const int wv = threadIdx.x >> 6, lane = threadIdx.x & 63;
    const int q = lane >> 4, l15 = lane & 15;
    const int cw = c0 + wv * 16;

    const ushort* abase = a_t + ((size_t)n * 64 + l15) * 1600 + q * 8;
    const float*  xbase = x + ((size_t)n * 512 + cw + l15) * 1600 + q * 8;

    f32x4 acc[4] = {};
    #pragma unroll 2
    for (int pc = 0; pc < 1600; pc += 32) {
        bf16x8 af[4];
        #pragma unroll
        for (int mt = 0; mt < 4; mt++)
            af[mt] = *(const bf16x8*)(abase + (size_t)mt * 16 * 1600 + pc);
        const float* xr = xbase + pc;
        float4 f0 = *(const float4*)(xr);
        float4 f1 = *(const float4*)(xr + 4);
        bf16x8 b;
        b[0] = (short)f2b(f0.x); b[1] = (short)f2b(f0.y);
        b[2] = (short)f2b(f0.z); b[3] = (short)f2b(f0.w);
        b[4] = (short)f2b(f1.x); b[5] = (short)f2b(f1.y);
        b[6] = (short)f2b(f1.z); b[7] = (short)f2b(f1.w);
        #pragma unroll
        for (int mt = 0; mt < 4; mt++)
            acc[mt] = __builtin_amdgcn_mfma_f32_16x16x32_bf16(af[mt], b, acc[mt], 0, 0, 0);
    }
    // D row = k = mt*16 + q*4 + r, col = c = cw + l15. Sole owner -> plain store.
    float* ob = out + (size_t)n * 32768 + cw + l15;
    #pragma unroll
    for (int mt = 0; mt < 4; mt++)
        #pragma unroll
        for (int r = 0; r < 4; r++)
            ob[(mt * 16 + q * 4 + r) * 512] = acc[mt][r];
}

// ------------------------------------------------- K4: merged one-pass epilogue
// per-n block: read raw slab, subtract asum*cent, rownorm2, gn, normalize, write.
__global__ __launch_bounds__(512) void k4(const float* __restrict__ vraw,
                                          const float* __restrict__ asum,
                                          const float* __restrict__ cent,
                                          float* __restrict__ out) {
    const int n = blockIdx.x;
    const int wv = threadIdx.x >> 6, lane = threadIdx.x & 63;
    __shared__ float stash[64 * 512];
    __shared__ float rs[64];
    __shared__ float gsh;

    #pragma unroll
    for (int i = 0; i < 8; i++) {
        const int k = wv * 8 + i;
        const size_t ro = (size_t)n * 32768 + (size_t)k * 512 + lane * 8;
        const float as = asum[n * 64 + k];
        const f32x4* pp = (const f32x4*)(vraw + ro);
        f32x4 a0 = pp[0], a1 = pp[1];
        const f32x4* cp = (const f32x4*)(cent + k * 512 + lane * 8);
        f32x4 v0 = a0 - cp[0] * as;
        f32x4 v1 = a1 - cp[1] * as;
        float s = 0.f;
        #pragma unroll
        for (int e = 0; e < 4; e++) { s = fmaf(v0[e], v0[e], s); s = fmaf(v1[e], v1[e], s); }
        *(f32x4*)&stash[k * 512 + lane * 8] = v0;
        *(f32x4*)&stash[k * 512 + lane * 8 + 4] = v1;
        #pragma unroll
        for (int off = 32; off > 0; off >>= 1) s += __shfl_down(s, off, 64);
        if (lane == 0) rs[k] = s;
    }
    __syncthreads();
    if (wv == 0) {
        float t = rs[lane];
        float d = fmaxf(sqrtf(t), EPSF);
        float r = t / (d * d);
        #pragma unroll
        for (int off = 32; off > 0; off >>= 1) r += __shfl_down(r, off, 64);
        if (lane == 0) gsh = fmaxf(sqrtf(r), EPSF);
    }
    __syncthreads();
    const float g = gsh;
    #pragma unroll
    for (int i = 0; i < 8; i++) {
        const int k = wv * 8 + i;
        const float inv = 1.f / (fmaxf(sqrtf(rs[k]), EPSF) * g);
        f32x4 v0 = *(const f32x4*)&stash[k * 512 + lane * 8];
        f32x4 v1 = *(const f32x4*)&stash[k * 512 + lane * 8 + 4];
        v0 *= inv;
        v1 *= inv;
        float* op = out + (size_t)n * 32768 + (size_t)k * 512 + lane * 8;
        *(f32x4*)op = v0;
        *(f32x4*)(op + 4) = v1;
    }
}

// -------------------------------------------------
extern "C" void kernel_launch(void* const* d_in, const int* in_sizes, int n_in,
                              void* d_out, int out_size, void* d_ws, size_t ws_size,
                              hipStream_t stream) {
    const float* x    = (const float*)d_in[0];
    const float* W    = (const float*)d_in[1];
    const float* cent = (const float*)d_in[2];
    float* out = (float*)d_out;
    char* ws = (char*)d_ws;

    ushort* a_t  = (ushort*)(ws + 0);
    ushort* Wb   = (ushort*)(ws + 13107200);
    float*  asum = (float*)(ws + 13172736);

    hipLaunchKernelGGL(k0_wb,     dim3(128),    dim3(256), 0, stream, W, Wb, asum);
    hipLaunchKernelGGL(k2g_gemm1, dim3(25, 64), dim3(128), 0, stream, x, Wb, a_t, asum);
    hipLaunchKernelGGL(k3_gemm2,  dim3(256),    dim3(512), 0, stream, a_t, x, out);
    hipLaunchKernelGGL(k4,        dim3(64),     dim3(512), 0, stream, out, asum, cent, out);
}